// Round 1
// baseline (347.899 us; speedup 1.0000x reference)
//
#include <hip/hip_runtime.h>
#include <math.h>

#define NPATH 2048
#define NS 512
#define NF 40
#define ROWS_OUT 513
#define DTC (1.0f / 512.0f)

// ws layout (floats):
//   [0..511]      w[m]
//   [512..1023]   cumw2[t] = sum_{m<=t} w[m]^2
//   [1024..1503]  per-forward constants, 12 per n:
//       0..2: nu*rho*L[n][0..2]   3: nu*sqrt(1-rho^2)
//       4: 0.5*nu^2*DT            5: mu0*DT
//       6..8: vol_scale*L[n][0..2] 9: F0[n]

__global__ __launch_bounds__(512) void precomp_kernel(
    const float* __restrict__ F0, const float* __restrict__ alphas,
    const float* __restrict__ rhos, const float* __restrict__ nus,
    const float* __restrict__ tau, const float* __restrict__ L,
    const float* __restrict__ Lam, float* __restrict__ ws)
{
    __shared__ double sc[NS];
    __shared__ float omega0[NF];
    __shared__ float vs_s[NF];
    int tid = threadIdx.x;

    // w[m] in double: ((m+1)^0.6 - m^0.6)/0.6 * DT^(-0.4) / Gamma(0.6)
    double m = (double)tid;
    double dt_alpha = pow(512.0, 0.4);          // DT^ALPHA = 512^0.4
    const double gamma06 = 1.4891922488128171;  // Gamma(0.6)
    double wv = (pow(m + 1.0, 0.6) - pow(m, 0.6)) * (1.0 / 0.6) * dt_alpha / gamma06;
    ws[tid] = (float)wv;
    sc[tid] = wv * wv;

    if (tid < NF) {
        float f0 = F0[tid];
        float eta = sqrtf(fabsf(f0 + 0.02f));
        float vs = alphas[tid] * eta;
        vs_s[tid] = vs;
        omega0[tid] = tau[tid] * vs / (1.0f + tau[tid] * f0);
    }
    __syncthreads();

    // Hillis-Steele inclusive scan of w^2 (double)
    for (int off = 1; off < NS; off <<= 1) {
        double u = (tid >= off) ? sc[tid - off] : 0.0;
        double v = sc[tid];
        __syncthreads();
        sc[tid] = v + u;
        __syncthreads();
    }
    ws[NS + tid] = (float)sc[tid];

    if (tid < NF) {
        int n = tid;
        float s = 0.0f;
        for (int j = 0; j < NF; ++j) s += Lam[n * NF + j] * omega0[j];
        float mu0 = -vs_s[n] * s;
        float rho = rhos[n], nu = nus[n];
        float* c = ws + 1024 + n * 12;
        c[0] = nu * rho * L[n * 3 + 0];
        c[1] = nu * rho * L[n * 3 + 1];
        c[2] = nu * rho * L[n * 3 + 2];
        c[3] = nu * sqrtf(fmaxf(1.0f - rho * rho, 0.0f));
        c[4] = 0.5f * nu * nu * DTC;
        c[5] = mu0 * DTC;
        c[6] = vs_s[n] * L[n * 3 + 0];
        c[7] = vs_s[n] * L[n * 3 + 1];
        c[8] = vs_s[n] * L[n * 3 + 2];
        c[9] = F0[n];
        c[10] = 0.0f;
        c[11] = 0.0f;
    }
}

// One block per path. 320 threads = 5 waves = 8 groups of 40 (one forward each).
__global__ __launch_bounds__(320) void path_kernel(
    const float4* __restrict__ dz, const float* __restrict__ ws,
    float* __restrict__ out)
{
    __shared__ float4 dz_s[NS];      // 8 KB
    __shared__ float4 fbm4_s[NS];    // 8 KB
    __shared__ float  wp[1024];      // zero-padded w: wp[511+m] = w[m], wp[<511]=0
    __shared__ float  cw2[NS];
    __shared__ float  chunk[64 * 41];// 64 steps x 40 fwd, stride 41 (bank-conflict-free)

    int tid = threadIdx.x;
    int p = blockIdx.x;

    for (int i = tid; i < 1023; i += 320) wp[i] = (i < 511) ? 0.0f : ws[i - 511];
    for (int i = tid; i < NS; i += 320) cw2[i] = ws[NS + i];
    for (int i = tid; i < NS; i += 320) dz_s[i] = dz[(size_t)p * NS + i];

    // per-thread constants for forward n = tid % 40 (fixed for all its elements)
    int n = tid % 40;
    const float* c = ws + 1024 + n * 12;
    float cA0 = c[0], cA1 = c[1], cA2 = c[2], cA3 = c[3];
    float ca = c[4], cm0 = c[5];
    float cB0 = c[6], cB1 = c[7], cB2 = c[8], cF0 = c[9];

    __syncthreads();

    // ---- Phase B: fbm4[t,:] = sum_s w[t-s] * dz[s,:]  (t = tid and 511-tid) ----
    if (tid < 256) {
        int ta = tid;
        float4 accA = make_float4(0.f, 0.f, 0.f, 0.f);
        float4 accB = make_float4(0.f, 0.f, 0.f, 0.f);
        const float* wpa = wp + 511 + ta;   // wpa[-s] = w[ta - s] (0 if s > ta)
        const float* wpb = wp + 1022 - ta;  // wpb[-s] = w[(511-ta) - s]
        #pragma unroll 4
        for (int s = 0; s < NS; ++s) {
            float4 d = dz_s[s];             // wave-broadcast read
            float wa = wpa[-s];
            float wb = wpb[-s];
            accA.x = fmaf(wa, d.x, accA.x);
            accA.y = fmaf(wa, d.y, accA.y);
            accA.z = fmaf(wa, d.z, accA.z);
            accA.w = fmaf(wa, d.w, accA.w);
            accB.x = fmaf(wb, d.x, accB.x);
            accB.y = fmaf(wb, d.y, accB.y);
            accB.z = fmaf(wb, d.z, accB.z);
            accB.w = fmaf(wb, d.w, accB.w);
        }
        fbm4_s[ta] = accA;
        fbm4_s[511 - ta] = accB;
    }
    __syncthreads();

    // ---- Phase C/D: dF, chunked inclusive scan over t, write ----
    float* outp = out + (size_t)p * (ROWS_OUT * NF);
    if (tid < NF) outp[tid] = cF0;          // row 0 = F0

    int wave = tid >> 6, lane = tid & 63;
    int tsub = tid / 40;                    // 0..7
    float carry[8];
    #pragma unroll
    for (int j = 0; j < 8; ++j) carry[j] = 0.0f;

    for (int cix = 0; cix < 8; ++cix) {
        int t0 = cix * 64;
        // compute dF into chunk
        #pragma unroll
        for (int k = 0; k < 8; ++k) {
            int tl = tsub + k * 8;          // 0..63
            int t = t0 + tl;
            float4 f = fbm4_s[t];
            float arg = f.x * cA0 + f.y * cA1 + f.z * cA2 + f.w * cA3 - ca * cw2[t];
            float uv = expf(arg);
            float4 d = dz_s[t];
            float wr = d.x * cB0 + d.y * cB1 + d.z * cB2;
            chunk[tl * 41 + n] = cm0 * uv * uv + wr * uv;
        }
        __syncthreads();
        // per-forward inclusive scan across the 64 steps (lane = step)
        #pragma unroll
        for (int j = 0; j < 8; ++j) {
            int nn = wave * 8 + j;
            float v = chunk[lane * 41 + nn];
            #pragma unroll
            for (int dlt = 1; dlt < 64; dlt <<= 1) {
                float o = __shfl_up(v, dlt, 64);
                v += (lane >= dlt) ? o : 0.0f;
            }
            v += carry[j];
            carry[j] = __shfl(v, 63, 64);
            chunk[lane * 41 + nn] = v;
        }
        __syncthreads();
        // coalesced write: address offset = (1+t0)*40 + k*320 + tid
        #pragma unroll
        for (int k = 0; k < 8; ++k) {
            int tl = tsub + k * 8;
            outp[(1 + t0 + tl) * NF + n] = cF0 + chunk[tl * 41 + n];
        }
        __syncthreads();
    }
}

extern "C" void kernel_launch(void* const* d_in, const int* in_sizes, int n_in,
                              void* d_out, int out_size, void* d_ws, size_t ws_size,
                              hipStream_t stream) {
    const float4* dz  = (const float4*)d_in[0];
    const float* F0   = (const float*)d_in[1];
    const float* alph = (const float*)d_in[2];
    const float* rhos = (const float*)d_in[3];
    const float* nus  = (const float*)d_in[4];
    const float* tau  = (const float*)d_in[5];
    const float* L    = (const float*)d_in[6];
    const float* Lam  = (const float*)d_in[7];
    float* ws = (float*)d_ws;
    float* out = (float*)d_out;

    int n_paths = in_sizes[0] / (NS * 4);

    precomp_kernel<<<1, 512, 0, stream>>>(F0, alph, rhos, nus, tau, L, Lam, ws);
    path_kernel<<<n_paths, 320, 0, stream>>>(dz, ws, out);
}

// Round 3
// 312.319 us; speedup vs baseline: 1.1139x; 1.1139x over previous
//
#include <hip/hip_runtime.h>
#include <math.h>

#define NS 512
#define NF 40
#define ROWS_OUT 513
#define DTC (1.0f / 512.0f)

// ws layout (floats):
//   [0..511]      w[m]
//   [512..1023]   cumw2[t] = sum_{m<=t} w[m]^2
//   [1024..1343]  per-forward constants, 8 per n:
//       0..2: cC = vol_scale*L[n]   3: q = nu*rho/vol_scale
//       4: cA3 = nu*sqrt(1-rho^2)   5: ca = 0.5*nu^2*DT
//       6: cm0 = mu0*DT             7: F0[n]

__global__ __launch_bounds__(512) void precomp_kernel(
    const float* __restrict__ F0, const float* __restrict__ alphas,
    const float* __restrict__ rhos, const float* __restrict__ nus,
    const float* __restrict__ tau, const float* __restrict__ L,
    const float* __restrict__ Lam, float* __restrict__ ws)
{
    __shared__ double sc[NS];
    __shared__ float omega0[NF];
    __shared__ float vs_s[NF];
    int tid = threadIdx.x;

    double m = (double)tid;
    double dt_alpha = pow(512.0, 0.4);          // DT^ALPHA = 512^0.4
    const double gamma06 = 1.4891922488128171;  // Gamma(0.6)
    double wv = (pow(m + 1.0, 0.6) - pow(m, 0.6)) * (1.0 / 0.6) * dt_alpha / gamma06;
    ws[tid] = (float)wv;
    sc[tid] = wv * wv;

    if (tid < NF) {
        float f0 = F0[tid];
        float eta = sqrtf(fabsf(f0 + 0.02f));
        float vs = alphas[tid] * eta;
        vs_s[tid] = vs;
        omega0[tid] = tau[tid] * vs / (1.0f + tau[tid] * f0);
    }
    __syncthreads();

    for (int off = 1; off < NS; off <<= 1) {
        double u = (tid >= off) ? sc[tid - off] : 0.0;
        double v = sc[tid];
        __syncthreads();
        sc[tid] = v + u;
        __syncthreads();
    }
    ws[NS + tid] = (float)sc[tid];

    if (tid < NF) {
        int n = tid;
        float s = 0.0f;
        for (int j = 0; j < NF; ++j) s += Lam[n * NF + j] * omega0[j];
        float vs = vs_s[n];
        float mu0 = -vs * s;
        float rho = rhos[n], nu = nus[n];
        float* c = ws + 1024 + n * 8;
        c[0] = vs * L[n * 3 + 0];
        c[1] = vs * L[n * 3 + 1];
        c[2] = vs * L[n * 3 + 2];
        c[3] = nu * rho / fmaxf(vs, 1e-30f);
        c[4] = nu * sqrtf(fmaxf(1.0f - rho * rho, 0.0f));
        c[5] = 0.5f * nu * nu * DTC;
        c[6] = mu0 * DTC;
        c[7] = F0[n];
    }
}

// ---- wave64 inclusive scan via DPP (pure VALU, no DS-pipe shuffles) ----
template<int CTRL, int RM>
__device__ __forceinline__ float dpp_add(float v) {
    int t = __builtin_amdgcn_update_dpp(0, __float_as_int(v), CTRL, RM, 0xf, true);
    return v + __int_as_float(t);
}
__device__ __forceinline__ float wave_iscan(float v) {
    v = dpp_add<0x111, 0xf>(v);   // row_shr:1
    v = dpp_add<0x112, 0xf>(v);   // row_shr:2
    v = dpp_add<0x114, 0xf>(v);   // row_shr:4
    v = dpp_add<0x118, 0xf>(v);   // row_shr:8  -> per-16-row scans
    v = dpp_add<0x142, 0xa>(v);   // row_bcast:15 -> rows 1,3
    v = dpp_add<0x143, 0xc>(v);   // row_bcast:31 -> rows 2,3
    return v;
}

__device__ __forceinline__ void fma4(float4& acc, float c, const float4& v) {
    acc.x = fmaf(c, v.x, acc.x);
    acc.y = fmaf(c, v.y, acc.y);
    acc.z = fmaf(c, v.z, acc.z);
    acc.w = fmaf(c, v.w, acc.w);
}

// One block per path. 320 threads = 5 waves.
__global__ __launch_bounds__(320, 4) void path_kernel(
    const float* __restrict__ dz, const float* __restrict__ ws,
    float* __restrict__ out)
{
    __shared__ float4 dz_s[NS];       // 8192 B (for phase C/D wr-term)
    __shared__ float4 fbm4_s[NS];     // 8192 B
    __shared__ float  wp[768];        // 3072 B: wp[j] = (j<256 ? 0 : w[j-256])
    __shared__ float  cw2[NS];        // 2048 B
    __shared__ float  chunk[64 * 41]; // 10496 B  (total 32000 B)

    int tid = threadIdx.x;
    int p = blockIdx.x;
    const float4* dzg = (const float4*)dz + (size_t)p * NS;

    for (int i = tid; i < 768; i += 320) wp[i] = (i < 256) ? 0.0f : ws[i - 256];
    for (int i = tid; i < NS; i += 320) { cw2[i] = ws[NS + i]; dz_s[i] = dzg[i]; }
    __syncthreads();

    // ---- Phase B: fbm4[t] = sum_s w[t-s]*dz[s]; 2 waves, 4 consecutive t/thread.
    // dz[s] is wave-uniform -> scalar (SGPR) global loads, no LDS broadcast.
    if (tid < 128) {
        int i = tid;                        // t0 = 4*i
        int gmax = (tid < 64) ? 64 : 128;   // wave0: t<256 -> s<256 (triangular skip)
        const float4* wp4 = (const float4*)wp;
        float4 a0 = make_float4(0.f, 0.f, 0.f, 0.f);
        float4 a1 = a0, a2 = a0, a3 = a0;
        #pragma unroll 2
        for (int g = 0; g < gmax; ++g) {
            float4 d0 = dzg[4 * g + 0];     // uniform address -> s_load
            float4 d1 = dzg[4 * g + 1];
            float4 d2 = dzg[4 * g + 2];
            float4 d3 = dzg[4 * g + 3];
            float4 lo = wp4[63 + i - g];    // lo = w[t0-s0-4 .. t0-s0-1]
            float4 hi = wp4[64 + i - g];    // hi = w[t0-s0 .. t0-s0+3]
            // s = 4g+k needs coeff w[t0+c-s] for t = t0+c
            fma4(a0, hi.x, d0); fma4(a1, hi.y, d0); fma4(a2, hi.z, d0); fma4(a3, hi.w, d0);
            fma4(a0, lo.w, d1); fma4(a1, hi.x, d1); fma4(a2, hi.y, d1); fma4(a3, hi.z, d1);
            fma4(a0, lo.z, d2); fma4(a1, lo.w, d2); fma4(a2, hi.x, d2); fma4(a3, hi.y, d2);
            fma4(a0, lo.y, d3); fma4(a1, lo.z, d3); fma4(a2, lo.w, d3); fma4(a3, hi.x, d3);
        }
        fbm4_s[4 * i + 0] = a0;
        fbm4_s[4 * i + 1] = a1;
        fbm4_s[4 * i + 2] = a2;
        fbm4_s[4 * i + 3] = a3;
    }

    // per-wave C/D constants (8 forwards per wave) held in VGPRs
    int lane = tid & 63;
    int wv = tid >> 6;
    float4 K0[8], K1[8];
    #pragma unroll
    for (int j = 0; j < 8; ++j) {
        const float4* c = (const float4*)(ws + 1024 + (wv * 8 + j) * 8);
        K0[j] = c[0];   // cC0,cC1,cC2,q
        K1[j] = c[1];   // cA3,ca,cm0,cF0
    }
    float carry[8];
    #pragma unroll
    for (int j = 0; j < 8; ++j) carry[j] = 0.0f;

    float* outp = out + (size_t)p * (ROWS_OUT * NF);
    if (tid < NF) outp[tid] = ws[1024 + tid * 8 + 7];   // row 0 = F0

    int n2 = tid % 40;
    int tsub = tid / 40;

    __syncthreads();

    // ---- Phase C/D: dF in lane=t order, DPP scan, transpose via chunk for
    // coalesced global writes.
    for (int cix = 0; cix < 8; ++cix) {
        int t = cix * 64 + lane;
        float4 f = fbm4_s[t];
        float4 d = dz_s[t];
        float cw = cw2[t];
        #pragma unroll
        for (int j = 0; j < 8; ++j) {
            float dotf = f.x * K0[j].x + f.y * K0[j].y + f.z * K0[j].z;
            float arg = fmaf(K0[j].w, dotf, fmaf(K1[j].x, f.w, -K1[j].y * cw));
            float uv = __expf(arg);
            float dotc = d.x * K0[j].x + d.y * K0[j].y + d.z * K0[j].z;
            float dF = fmaf(K1[j].z * uv, uv, dotc * uv);
            float v = wave_iscan(dF) + carry[j];
            carry[j] = __int_as_float(__builtin_amdgcn_readlane(__float_as_int(v), 63));
            chunk[lane * 41 + wv * 8 + j] = v + K1[j].w;
        }
        __syncthreads();
        #pragma unroll
        for (int k = 0; k < 8; ++k) {
            int tl = tsub + k * 8;
            outp[(1 + cix * 64 + tl) * NF + n2] = chunk[tl * 41 + n2];
        }
        __syncthreads();
    }
}

extern "C" void kernel_launch(void* const* d_in, const int* in_sizes, int n_in,
                              void* d_out, int out_size, void* d_ws, size_t ws_size,
                              hipStream_t stream) {
    const float* dz   = (const float*)d_in[0];
    const float* F0   = (const float*)d_in[1];
    const float* alph = (const float*)d_in[2];
    const float* rhos = (const float*)d_in[3];
    const float* nus  = (const float*)d_in[4];
    const float* tau  = (const float*)d_in[5];
    const float* L    = (const float*)d_in[6];
    const float* Lam  = (const float*)d_in[7];
    float* ws = (float*)d_ws;
    float* out = (float*)d_out;

    int n_paths = in_sizes[0] / (NS * 4);

    precomp_kernel<<<1, 512, 0, stream>>>(F0, alph, rhos, nus, tau, L, Lam, ws);
    path_kernel<<<n_paths, 320, 0, stream>>>(dz, ws, out);
}

// Round 4
// 264.036 us; speedup vs baseline: 1.3176x; 1.1829x over previous
//
#include <hip/hip_runtime.h>
#include <math.h>

#define NS 512
#define NF 40
#define ROWS_OUT 513
#define DTC (1.0f / 512.0f)
#define PLANE 520   // floats per component plane (512 + 8 pad)

// ws layout (floats):
//   [0..511]      w[m]            (host-computed, fp64)
//   [512..1023]   cumw2[t]        (host-computed, fp64 prefix)
//   [1024..1343]  per-forward constants, 8 per n:
//       0..2: cC = vol_scale*L[n]   3: q = nu*rho/vol_scale
//       4: cA3 = nu*sqrt(1-rho^2)   5: ca = 0.5*nu^2*DT
//       6: cm0 = mu0*DT             7: F0[n]

__global__ __launch_bounds__(64) void const_kernel(
    const float* __restrict__ F0, const float* __restrict__ alphas,
    const float* __restrict__ rhos, const float* __restrict__ nus,
    const float* __restrict__ tau, const float* __restrict__ L,
    const float* __restrict__ Lam, float* __restrict__ ws)
{
    __shared__ float omega0[NF];
    __shared__ float vs_s[NF];
    int n = threadIdx.x;
    if (n < NF) {
        float f0 = F0[n];
        float vs = alphas[n] * sqrtf(fabsf(f0 + 0.02f));
        vs_s[n] = vs;
        omega0[n] = tau[n] * vs / (1.0f + tau[n] * f0);
    }
    __syncthreads();
    if (n < NF) {
        float s = 0.0f;
        for (int j = 0; j < NF; ++j) s += Lam[n * NF + j] * omega0[j];
        float vs = vs_s[n];
        float mu0 = -vs * s;
        float rho = rhos[n], nu = nus[n];
        float* c = ws + 1024 + n * 8;
        c[0] = vs * L[n * 3 + 0];
        c[1] = vs * L[n * 3 + 1];
        c[2] = vs * L[n * 3 + 2];
        c[3] = nu * rho / fmaxf(vs, 1e-30f);
        c[4] = nu * sqrtf(fmaxf(1.0f - rho * rho, 0.0f));
        c[5] = 0.5f * nu * nu * DTC;
        c[6] = mu0 * DTC;
        c[7] = F0[n];
    }
}

// ---- wave64 inclusive scan via DPP (pure VALU) ----
template<int CTRL, int RM>
__device__ __forceinline__ float dpp_add(float v) {
    int t = __builtin_amdgcn_update_dpp(0, __float_as_int(v), CTRL, RM, 0xf, true);
    return v + __int_as_float(t);
}
__device__ __forceinline__ float wave_iscan(float v) {
    v = dpp_add<0x111, 0xf>(v);   // row_shr:1
    v = dpp_add<0x112, 0xf>(v);   // row_shr:2
    v = dpp_add<0x114, 0xf>(v);   // row_shr:4
    v = dpp_add<0x118, 0xf>(v);   // row_shr:8
    v = dpp_add<0x142, 0xa>(v);   // row_bcast:15 -> rows 1,3
    v = dpp_add<0x143, 0xc>(v);   // row_bcast:31 -> rows 2,3
    return v;
}

__device__ __forceinline__ void fma4(float4& acc, float c, const float4& v) {
    acc.x = fmaf(c, v.x, acc.x);
    acc.y = fmaf(c, v.y, acc.y);
    acc.z = fmaf(c, v.z, acc.z);
    acc.w = fmaf(c, v.w, acc.w);
}

// 256 threads = 4 waves; 2 paths per block.
__global__ __launch_bounds__(256, 4) void path_kernel(
    const float* __restrict__ dz, const float* __restrict__ ws,
    float* __restrict__ out)
{
    __shared__ float planes[2 * 4 * PLANE]; // 16640 B: fbm4, component-major
    __shared__ float wp[768];               // 3072 B: wp[j] = (j<256 ? 0 : w[j-256])
    __shared__ float cw2[NS];               // 2048 B
    __shared__ float chunk[64 * 41];        // 10496 B  (total 32256 B)

    int tid = threadIdx.x;
    int lane = tid & 63;
    int wv = __builtin_amdgcn_readfirstlane(tid >> 6);
    int pA = blockIdx.x * 2, pB = pA + 1;
    const float4* dzgA = (const float4*)dz + (size_t)pA * NS;
    const float4* dzgB = (const float4*)dz + (size_t)pB * NS;

    for (int i = tid; i < 768; i += 256) wp[i] = (i < 256) ? 0.0f : ws[i - 256];
    for (int i = tid; i < NS; i += 256) cw2[i] = ws[NS + i];
    __syncthreads();

    // ---- Phase B: fbm4[t] = sum_s w[t-s]*dz[s]; all 4 waves.
    // wave = {pathA-lo, pathA-hi, pathB-lo, pathB-hi}; 4 consecutive t/thread.
    {
        int path = wv >> 1;
        int half = wv & 1;
        int i = half * 64 + lane;           // quad index: t = 4i..4i+3
        int gmax = half ? 128 : 64;         // triangular skip at wave granularity
        const float4* dzg = path ? dzgB : dzgA;
        float* pf = planes + path * 4 * PLANE;
        const float4* wp4 = (const float4*)wp;
        float4 a0 = make_float4(0.f, 0.f, 0.f, 0.f);
        float4 a1 = a0, a2 = a0, a3 = a0;
        #pragma unroll 2
        for (int g = 0; g < gmax; ++g) {
            float4 d0 = dzg[4 * g + 0];     // wave-uniform address
            float4 d1 = dzg[4 * g + 1];
            float4 d2 = dzg[4 * g + 2];
            float4 d3 = dzg[4 * g + 3];
            float4 lo = wp4[63 + i - g];    // w[t0-s0-4 .. t0-s0-1]
            float4 hi = wp4[64 + i - g];    // w[t0-s0 .. t0-s0+3]
            fma4(a0, hi.x, d0); fma4(a1, hi.y, d0); fma4(a2, hi.z, d0); fma4(a3, hi.w, d0);
            fma4(a0, lo.w, d1); fma4(a1, hi.x, d1); fma4(a2, hi.y, d1); fma4(a3, hi.z, d1);
            fma4(a0, lo.z, d2); fma4(a1, lo.w, d2); fma4(a2, hi.x, d2); fma4(a3, hi.y, d2);
            fma4(a0, lo.y, d3); fma4(a1, lo.z, d3); fma4(a2, lo.w, d3); fma4(a3, hi.x, d3);
        }
        // component-major planes: lane-stride-16B b128 writes, conflict-free
        ((float4*)(pf + 0 * PLANE))[i] = make_float4(a0.x, a1.x, a2.x, a3.x);
        ((float4*)(pf + 1 * PLANE))[i] = make_float4(a0.y, a1.y, a2.y, a3.y);
        ((float4*)(pf + 2 * PLANE))[i] = make_float4(a0.z, a1.z, a2.z, a3.z);
        ((float4*)(pf + 3 * PLANE))[i] = make_float4(a0.w, a1.w, a2.w, a3.w);
    }

    float carryA[10], carryB[10];
    #pragma unroll
    for (int j = 0; j < 10; ++j) { carryA[j] = 0.0f; carryB[j] = 0.0f; }

    float* outA = out + (size_t)pA * (ROWS_OUT * NF);
    float* outB = out + (size_t)pB * (ROWS_OUT * NF);
    if (tid < NF) outA[tid] = ws[1024 + tid * 8 + 7];               // row 0 = F0
    if (tid >= 64 && tid < 64 + NF) outB[tid - 64] = ws[1024 + (tid - 64) * 8 + 7];

    __syncthreads();

    // ---- Phase C/D: per chunk of 64 t (lane = t): dF, DPP scan, transpose, store.
    for (int cix = 0; cix < 8; ++cix) {
        int t = cix * 64 + lane;
        float cw = cw2[t];
        #pragma unroll
        for (int path = 0; path < 2; ++path) {
            const float* pf = planes + path * 4 * PLANE;
            float fx = pf[t], fy = pf[PLANE + t], fz = pf[2 * PLANE + t], fw = pf[3 * PLANE + t];
            float4 d = path ? dzgB[t] : dzgA[t];
            float* carry = path ? carryB : carryA;
            #pragma unroll
            for (int j = 0; j < 10; ++j) {
                int n = wv * 10 + j;                 // wave-uniform -> scalar loads
                const float* c = ws + 1024 + n * 8;
                float cC0 = c[0], cC1 = c[1], cC2 = c[2], q = c[3];
                float cA3 = c[4], ca = c[5], cm0 = c[6], f0 = c[7];
                float dotf = fx * cC0 + fy * cC1 + fz * cC2;
                float arg = fmaf(q, dotf, fmaf(cA3, fw, -ca * cw));
                float uv = __expf(arg);
                float dotc = d.x * cC0 + d.y * cC1 + d.z * cC2;
                float dF = uv * fmaf(cm0, uv, dotc);
                float v = wave_iscan(dF) + carry[j];
                carry[j] = __int_as_float(__builtin_amdgcn_readlane(__float_as_int(v), 63));
                chunk[lane * 41 + n] = v + f0;
            }
            __syncthreads();
            float* o = (path ? outB : outA) + NF + cix * (64 * NF);
            #pragma unroll
            for (int k = 0; k < 10; ++k) {
                int f = tid + k * 256;               // 2560 = 64 rows x 40 fwd, contiguous
                __builtin_nontemporal_store(chunk[f + f / 40], o + f);
            }
            __syncthreads();
        }
    }
}

extern "C" void kernel_launch(void* const* d_in, const int* in_sizes, int n_in,
                              void* d_out, int out_size, void* d_ws, size_t ws_size,
                              hipStream_t stream) {
    const float* dz   = (const float*)d_in[0];
    const float* F0   = (const float*)d_in[1];
    const float* alph = (const float*)d_in[2];
    const float* rhos = (const float*)d_in[3];
    const float* nus  = (const float*)d_in[4];
    const float* tau  = (const float*)d_in[5];
    const float* L    = (const float*)d_in[6];
    const float* Lam  = (const float*)d_in[7];
    float* ws = (float*)d_ws;
    float* out = (float*)d_out;

    int n_paths = in_sizes[0] / (NS * 4);

    // w[] and cumw2[] depend on no device inputs: compute on host in fp64,
    // identical values every call; static buffer persists for graph replay.
    static float h_w[1024];
    {
        const double g06 = 1.4891922488128171;      // Gamma(0.6)
        double dta = pow(512.0, 0.4);               // DT^ALPHA
        double acc = 0.0;
        for (int m = 0; m < 512; ++m) {
            double wv = (pow((double)m + 1.0, 0.6) - pow((double)m, 0.6)) * (1.0 / 0.6) * dta / g06;
            h_w[m] = (float)wv;
            acc += wv * wv;
            h_w[512 + m] = (float)acc;
        }
    }
    hipMemcpyAsync(ws, h_w, sizeof(h_w), hipMemcpyHostToDevice, stream);

    const_kernel<<<1, 64, 0, stream>>>(F0, alph, rhos, nus, tau, L, Lam, ws);
    path_kernel<<<n_paths / 2, 256, 0, stream>>>(dz, ws, out);
}